// Round 10
// baseline (156.049 us; speedup 1.0000x reference)
//
#include <hip/hip_runtime.h>
#include <hip/hip_fp16.h>

// GraphConv: out[b,v,u] = relu( sum_{r,c} gather(nodes)[b,v,r,c] * kernel[r*C+c,u] + bias[u] )
// B=16, V=10000, R=8, C=64, U=64.  M=160000 rows, K=512, N=64.
//
// Round 10 = round 8 resubmitted (two broker timeouts; kernel never ran).
// Evidence from round 7 (81 us): MfmaUtil 15.5 / VALUBusy 21.5 / HBM 14% / Occ 17.7
//   -> latency-bound; VGPR=56 proves no compiler load pipelining across r.
// Changes vs round 7:
//   1) Explicit SW pipeline (T14): issue r+1's 8x float4 gather loads BEFORE the
//      convert+MFMA of r. Addresses all known at loop entry (branchless clamp).
//   2) B-fragment prepack once per grid into d_ws (128 KiB) by a tiny kernel;
//      per-block staging becomes a pure uint4 copy (no VALU convert per block).
// Unchanged: 3-term f16 hi/lo split (x2048 lo prescale), mfma_f32_32x32x16_f16,
//   128 KiB LDS B hi+lo lane-contiguous (conflict-free), branchless masked gather,
//   nontemporal stores, b = blockIdx&15 XCD round-robin.
// Pre-planned next lever (NOT applied; isolate one variable): N-split 2 blocks/CU
//   occupancy variant if this still lands >45 us with idle pipes.

#define Bn 16
#define Vn 10000
#define Rn 8
#define Cn 64
#define Un 64

#define LOSCALE 2048.0f
#define LOINV   (1.0f/2048.0f)

typedef _Float16      f16x8   __attribute__((ext_vector_type(8)));
typedef __fp16        fp16x2  __attribute__((ext_vector_type(2)));   // cvt_pkrtz return type
typedef float         f32x16  __attribute__((ext_vector_type(16)));
typedef unsigned int  u32x4   __attribute__((ext_vector_type(4)));
typedef unsigned short us8    __attribute__((ext_vector_type(8)));

__device__ __forceinline__ unsigned short f16b(_Float16 h) {
    return __builtin_bit_cast(unsigned short, h);
}
__device__ __forceinline__ unsigned int cvt2w(float a0, float a1) {
    const fp16x2 p = __builtin_amdgcn_cvt_pkrtz(a0, a1);
    return __builtin_bit_cast(unsigned int, p);
}
__device__ __forceinline__ _Float16 loh(unsigned int w) {
    return __builtin_bit_cast(_Float16, (unsigned short)(w & 0xffff));
}
__device__ __forceinline__ _Float16 hih(unsigned int w) {
    return __builtin_bit_cast(_Float16, (unsigned short)(w >> 16));
}

// LDS/ws layout: group gg = f*64 + lane, f = nt*32 + kt in [0,64):
//   hi plane: byte gg*16, lo plane: byte 65536 + gg*16  (16 B per (frag,lane))
#define LDS_LO 65536

// ---------------------------------------------------------------------------
// Prepack kernel: kern (f32 512x64) -> MFMA B fragments, f16 hi/lo, into ws.
// 4096 (frag,lane) groups; grid 16 x 256.
// ---------------------------------------------------------------------------
__global__ __launch_bounds__(256)
void prepack_b(const float* __restrict__ kern, unsigned char* __restrict__ ws) {
    const int g  = blockIdx.x * 256 + threadIdx.x;   // 0..4095
    const int f  = g >> 6;
    const int l  = g & 63;
    const int nt = f >> 5;
    const int kt = f & 31;
    const int n  = nt * 32 + (l & 31);
    const int kb = kt * 16 + ((l >> 5) << 3);
    us8 hh, ll;
    #pragma unroll
    for (int j = 0; j < 8; ++j) {
        const float x = kern[(kb + j) * Un + n];
        const _Float16 h  = (_Float16)x;
        const _Float16 lo = (_Float16)((x - (float)h) * LOSCALE);
        hh[j] = f16b(h);
        ll[j] = f16b(lo);
    }
    *(us8*)(ws + (size_t)g * 16)          = hh;
    *(us8*)(ws + LDS_LO + (size_t)g * 16) = ll;
}

// ---------------------------------------------------------------------------
// Main kernel. FAST: B staged by plain uint4 copy from prepacked ws.
// ---------------------------------------------------------------------------
template <bool FAST>
__global__ __launch_bounds__(512, 2)
void graphconv_kernel(const float* __restrict__ nodes,
                      const int* __restrict__ mapping,
                      const float* __restrict__ kern,
                      const float* __restrict__ bias,
                      const unsigned char* __restrict__ ws,
                      float* __restrict__ out) {
    extern __shared__ unsigned char lds[];   // 131072 B
    const int tid  = threadIdx.x;
    const int lane = tid & 63;
    const int w    = tid >> 6;               // wave 0..7
    const int g    = blockIdx.x;
    const int b    = g & 15;                 // batch; round-robin over XCDs
    const int v0   = (g >> 4) << 8;          // 256 rows per block

    const int row = lane & 31;
    const int grp = lane >> 5;               // which K-half of each fragment
    const int v   = v0 + w * 32 + row;
    const bool vok = v < Vn;

    // ---- preload this row's 8 mapping entries FIRST (latency hides under staging) ----
    int4 m03 = make_int4(-1, -1, -1, -1), m47 = make_int4(-1, -1, -1, -1);
    if (vok) {
        const int4* mp4 = (const int4*)(mapping + ((size_t)b * Vn + v) * Rn);
        m03 = mp4[0];
        m47 = mp4[1];
    }

    // ---- stage B fragments into LDS ----
    if (FAST) {
        const uint4* srcw = (const uint4*)ws;     // 8192 uint4 = 128 KiB
        uint4* dstw = (uint4*)lds;
        #pragma unroll
        for (int i = 0; i < 16; ++i) dstw[i * 512 + tid] = srcw[i * 512 + tid];
    } else {
        #pragma unroll
        for (int it = 0; it < 8; ++it) {
            const int gg = it * 512 + tid;
            const int f  = gg >> 6;
            const int l  = gg & 63;
            const int nt = f >> 5;
            const int kt = f & 31;
            const int n  = nt * 32 + (l & 31);
            const int kb = kt * 16 + ((l >> 5) << 3);
            us8 hh, ll;
            #pragma unroll
            for (int j = 0; j < 8; ++j) {
                const float x = kern[(kb + j) * Un + n];
                const _Float16 h  = (_Float16)x;
                const _Float16 lo = (_Float16)((x - (float)h) * LOSCALE);
                hh[j] = f16b(h);
                ll[j] = f16b(lo);
            }
            *(us8*)(lds + (size_t)gg * 16)          = hh;
            *(us8*)(lds + LDS_LO + (size_t)gg * 16) = ll;
        }
    }
    __syncthreads();

    int mv[8];
    mv[0] = m03.x; mv[1] = m03.y; mv[2] = m03.z; mv[3] = m03.w;
    mv[4] = m47.x; mv[5] = m47.y; mv[6] = m47.z; mv[7] = m47.w;

    // All 8 gather base pointers + masks computed up front (branchless).
    const float* srcs[8];
    unsigned int keep[8];
    #pragma unroll
    for (int r = 0; r < Rn; ++r) {
        const int mi = mv[r];
        keep[r] = (mi >= 0) ? 0xffffffffu : 0u;
        srcs[r] = nodes + ((size_t)b * Vn + (mi >= 0 ? mi : 0)) * Cn + grp * 8;
    }

    f32x16 am0 = {0,0,0,0,0,0,0,0,0,0,0,0,0,0,0,0};
    f32x16 am1 = {0,0,0,0,0,0,0,0,0,0,0,0,0,0,0,0};
    f32x16 ac0 = {0,0,0,0,0,0,0,0,0,0,0,0,0,0,0,0};
    f32x16 ac1 = {0,0,0,0,0,0,0,0,0,0,0,0,0,0,0,0};

    // ---- software-pipelined gather: issue r+1's loads before computing r ----
    float4 ca[4], cb4[4], na[4], nb4[4];
    #pragma unroll
    for (int kk = 0; kk < 4; ++kk) {
        ca[kk]  = *(const float4*)(srcs[0] + kk * 16);
        cb4[kk] = *(const float4*)(srcs[0] + kk * 16 + 4);
    }

    #pragma unroll
    for (int r = 0; r < Rn; ++r) {
        // issue next iteration's loads first: they overlap convert+MFMA below
        if (r + 1 < Rn) {
            #pragma unroll
            for (int kk = 0; kk < 4; ++kk) {
                na[kk]  = *(const float4*)(srcs[r + 1] + kk * 16);
                nb4[kk] = *(const float4*)(srcs[r + 1] + kk * 16 + 4);
            }
        }
        // convert current r's rows to f16 hi/lo, masked
        const unsigned int kp = keep[r];
        f16x8 ah[4], al[4];
        #pragma unroll
        for (int kk = 0; kk < 4; ++kk) {
            const float4 xa = ca[kk];
            const float4 xb = cb4[kk];
            u32x4 hw, lw;
            hw[0] = cvt2w(xa.x, xa.y); hw[1] = cvt2w(xa.z, xa.w);
            hw[2] = cvt2w(xb.x, xb.y); hw[3] = cvt2w(xb.z, xb.w);
            lw[0] = cvt2w((xa.x - (float)loh(hw[0])) * LOSCALE,
                          (xa.y - (float)hih(hw[0])) * LOSCALE);
            lw[1] = cvt2w((xa.z - (float)loh(hw[1])) * LOSCALE,
                          (xa.w - (float)hih(hw[1])) * LOSCALE);
            lw[2] = cvt2w((xb.x - (float)loh(hw[2])) * LOSCALE,
                          (xb.y - (float)hih(hw[2])) * LOSCALE);
            lw[3] = cvt2w((xb.z - (float)loh(hw[3])) * LOSCALE,
                          (xb.w - (float)hih(hw[3])) * LOSCALE);
            #pragma unroll
            for (int q = 0; q < 4; ++q) { hw[q] &= kp; lw[q] &= kp; }
            ah[kk] = __builtin_bit_cast(f16x8, hw);
            al[kk] = __builtin_bit_cast(f16x8, lw);
        }
        // MFMA block for r
        #pragma unroll
        for (int kk = 0; kk < 4; ++kk) {
            const int kt = r * 4 + kk;
            const size_t fb0 = (size_t)(kt)      * 1024 + (size_t)lane * 16;  // nt=0
            const size_t fb1 = (size_t)(32 + kt) * 1024 + (size_t)lane * 16;  // nt=1
            const f16x8 bh0 = __builtin_bit_cast(f16x8, *(const us8*)(lds + fb0));
            const f16x8 bl0 = __builtin_bit_cast(f16x8, *(const us8*)(lds + LDS_LO + fb0));
            const f16x8 bh1 = __builtin_bit_cast(f16x8, *(const us8*)(lds + fb1));
            const f16x8 bl1 = __builtin_bit_cast(f16x8, *(const us8*)(lds + LDS_LO + fb1));
            am0 = __builtin_amdgcn_mfma_f32_32x32x16_f16(ah[kk], bh0, am0, 0, 0, 0);
            ac0 = __builtin_amdgcn_mfma_f32_32x32x16_f16(al[kk], bh0, ac0, 0, 0, 0);
            ac0 = __builtin_amdgcn_mfma_f32_32x32x16_f16(ah[kk], bl0, ac0, 0, 0, 0);
            am1 = __builtin_amdgcn_mfma_f32_32x32x16_f16(ah[kk], bh1, am1, 0, 0, 0);
            ac1 = __builtin_amdgcn_mfma_f32_32x32x16_f16(al[kk], bh1, ac1, 0, 0, 0);
            ac1 = __builtin_amdgcn_mfma_f32_32x32x16_f16(ah[kk], bl1, ac1, 0, 0, 0);
        }
        // rotate (pure SSA renames after full unroll)
        if (r + 1 < Rn) {
            #pragma unroll
            for (int kk = 0; kk < 4; ++kk) { ca[kk] = na[kk]; cb4[kk] = nb4[kk]; }
        }
    }

    // ---- epilogue: combine hi/lo, bias, relu, nontemporal store ----
    const int n0    = lane & 31;
    const float bv0 = bias[n0];
    const float bv1 = bias[32 + n0];
    const int rbase = v0 + w * 32 + 4 * grp;
    #pragma unroll
    for (int q = 0; q < 16; ++q) {
        const int vv = rbase + (q & 3) + 8 * (q >> 2);
        if (vv < Vn) {
            float* o = out + ((size_t)b * Vn + vv) * Un;
            const float x0 = am0[q] + ac0[q] * LOINV + bv0;
            const float x1 = am1[q] + ac1[q] * LOINV + bv1;
            __builtin_nontemporal_store(x0 > 0.f ? x0 : 0.f, o + n0);
            __builtin_nontemporal_store(x1 > 0.f ? x1 : 0.f, o + 32 + n0);
        }
    }
}

extern "C" void kernel_launch(void* const* d_in, const int* in_sizes, int n_in,
                              void* d_out, int out_size, void* d_ws, size_t ws_size,
                              hipStream_t stream) {
    (void)in_sizes; (void)n_in; (void)out_size;
    const float* nodes   = (const float*)d_in[0];
    const int*   mapping = (const int*)d_in[1];
    const float* kern    = (const float*)d_in[2];
    const float* bias    = (const float*)d_in[3];
    float* out = (float*)d_out;
    unsigned char* ws = (unsigned char*)d_ws;

    static const int lds_bytes = 131072;
    const bool fast = (ws != nullptr) && (ws_size >= 131072);

    if (fast) {
        hipLaunchKernelGGL(prepack_b, dim3(16), dim3(256), 0, stream, kern, ws);
        (void)hipFuncSetAttribute(
            reinterpret_cast<const void*>(&graphconv_kernel<true>),
            hipFuncAttributeMaxDynamicSharedMemorySize, lds_bytes);
        hipLaunchKernelGGL(HIP_KERNEL_NAME(graphconv_kernel<true>),
                           dim3(16 * 40), dim3(512), lds_bytes, stream,
                           nodes, mapping, kern, bias, ws, out);
    } else {
        (void)hipFuncSetAttribute(
            reinterpret_cast<const void*>(&graphconv_kernel<false>),
            hipFuncAttributeMaxDynamicSharedMemorySize, lds_bytes);
        hipLaunchKernelGGL(HIP_KERNEL_NAME(graphconv_kernel<false>),
                           dim3(16 * 40), dim3(512), lds_bytes, stream,
                           nodes, mapping, kern, bias, ws, out);
    }
}